// Round 17
// baseline (273.097 us; speedup 1.0000x reference)
//
#include <hip/hip_runtime.h>

typedef __bf16 bf16x8 __attribute__((ext_vector_type(8)));
typedef float f32x4 __attribute__((ext_vector_type(4)));

__device__ __forceinline__ unsigned short f2bf(float f) {
  unsigned u = __builtin_bit_cast(unsigned, f);
  u += 0x7fffu + ((u >> 16) & 1u);
  return (unsigned short)(u >> 16);
}
__device__ __forceinline__ float bf2f(unsigned short h) {
  unsigned u = ((unsigned)h) << 16;
  return __builtin_bit_cast(float, u);
}
__device__ __forceinline__ void gload16(const void* g, void* l) {
  __builtin_amdgcn_global_load_lds((const __attribute__((address_space(1))) void*)g,
                                   (__attribute__((address_space(3))) void*)l, 16, 0, 0);
}
// byte permutation within a 128-byte K-panel row: k = kk*32+g*8+e -> byte g*32+kk*8+e
__device__ __forceinline__ int perm7(int x) {
  return ((x >> 3) & 3) * 32 + ((x >> 5) << 3) + (x & 7);
}

// ---------------- phase A ----------------

// Per block (2 n-values): mean_t(x) -> @W_Q0 -> contract with 64 W_QS rows -> pqs[blk]
__global__ __launch_bounds__(256) void k_qs(const float* __restrict__ x,
                                            const float* __restrict__ W_Q0,
                                            const float* __restrict__ W_QS,
                                            float* __restrict__ pqs) {
  __shared__ __align__(16) float w0[1024];
  __shared__ __align__(16) float lm[1024];
  __shared__ float lq[1024];
  __shared__ float red[4][16][64];
  const int tid = threadIdx.x;
#pragma unroll
  for (int i = 0; i < 4; ++i) w0[tid + i * 256] = W_Q0[tid + i * 256];
  const int n0 = blockIdx.x * 2;

  {
    const int b = tid >> 4, r = tid & 15, n = r >> 3, k4 = r & 7;
    const float4* xp = (const float4*)(x + ((size_t)(b * 2048 + n0 + n) * 12) * 32) + k4;
    float4 s0 = xp[0], s1 = xp[8], s2 = xp[16];
    float4 s3 = xp[24], s4 = xp[32], s5 = xp[40];
#pragma unroll
    for (int t = 6; t < 12; ++t) {
      float4 v = xp[t * 8];
      s0.x += v.x; s0.y += v.y; s0.z += v.z; s0.w += v.w;
      float4 tmp = s0; s0 = s1; s1 = s2; s2 = s3; s3 = s4; s4 = s5; s5 = tmp;
    }
    float4 m;
    m.x = (s0.x + s1.x + s2.x) + (s3.x + s4.x + s5.x);
    m.y = (s0.y + s1.y + s2.y) + (s3.y + s4.y + s5.y);
    m.z = (s0.z + s1.z + s2.z) + (s3.z + s4.z + s5.z);
    m.w = (s0.w + s1.w + s2.w) + (s3.w + s4.w + s5.w);
    const float inv12 = 1.0f / 12.0f;
    m.x *= inv12; m.y *= inv12; m.z *= inv12; m.w *= inv12;
    *(float4*)(lm + (b * 2 + n) * 32 + k4 * 4) = m;
  }
  __syncthreads();
#pragma unroll
  for (int j = 0; j < 4; ++j) {
    int i = tid + j * 256;
    int bn = i >> 5, q = i & 31;
    const float* mrow = &lm[bn * 32];
    float a = 0.f;
#pragma unroll
    for (int k = 0; k < 32; ++k) a += mrow[k] * w0[k * 32 + q];
    lq[i] = a;
  }
  __syncthreads();
  const int lane = tid & 63, w = tid >> 6;
  float acc[16];
#pragma unroll
  for (int b = 0; b < 16; ++b) acc[b] = 0.f;
#pragma unroll
  for (int rl = 0; rl < 16; ++rl) {
    int r = w * 16 + rl;
    float wv = W_QS[(size_t)(n0 * 32 + r) * 64 + lane];
#pragma unroll
    for (int b = 0; b < 16; ++b) acc[b] += lq[b * 64 + r] * wv;
  }
#pragma unroll
  for (int b = 0; b < 16; ++b) red[w][b][lane] = acc[b];
  __syncthreads();
#pragma unroll
  for (int it = 0; it < 4; ++it) {
    int idx = tid + it * 256;
    float s = red[0][idx >> 6][idx & 63] + red[1][idx >> 6][idx & 63] +
              red[2][idx >> 6][idx & 63] + red[3][idx >> 6][idx & 63];
    pqs[(size_t)blockIdx.x * 1024 + idx] = s;
  }
}

// Head-attention weights: pqs/pxmn_p reduce + qt + softmax -> at_g[16][8]
__global__ __launch_bounds__(256) void k_head(const float* __restrict__ pqs,
                                              const float* __restrict__ pxmn_p,
                                              const float* __restrict__ W_Q0,
                                              const float* __restrict__ W_QT,
                                              const float* __restrict__ K_T,
                                              const float* __restrict__ K_S,
                                              float* __restrict__ at_g) {
  const int b = blockIdx.x, tid = threadIdx.x;
  __shared__ float red[4][64];
  __shared__ float qs_s[64];
  __shared__ float xmn_s[384];
  __shared__ float xp[384];
  __shared__ float qtp[4][64];

  {
    const int q = tid >> 6, dk = tid & 63;
    const float* p = pqs + (size_t)(q * 256) * 1024 + b * 64 + dk;
    float s0 = 0.f, s1 = 0.f, s2 = 0.f, s3 = 0.f;
#pragma unroll
    for (int c = 0; c < 256; c += 4) {
      s0 += p[(size_t)(c + 0) * 1024];
      s1 += p[(size_t)(c + 1) * 1024];
      s2 += p[(size_t)(c + 2) * 1024];
      s3 += p[(size_t)(c + 3) * 1024];
    }
    red[q][dk] = (s0 + s1) + (s2 + s3);
  }
  for (int i = tid; i < 384; i += 256) {
    int t = i >> 5, k = i & 31;
    const float* p = pxmn_p + (size_t)((b * 12 + t) * 8) * 32 + k;
    float v = ((p[0] + p[32]) + (p[64] + p[96])) + ((p[128] + p[160]) + (p[192] + p[224]));
    xmn_s[i] = v * (1.0f / 2048.0f);
  }
  __syncthreads();
  for (int i = tid; i < 384; i += 256) {
    int t = i >> 5, q = i & 31;
    float a = 0.f;
#pragma unroll
    for (int k = 0; k < 32; ++k) a += xmn_s[t * 32 + k] * W_Q0[k * 32 + q];
    xp[i] = a;
  }
  if (tid < 64) qs_s[tid] = red[0][tid] + red[1][tid] + red[2][tid] + red[3][tid];
  __syncthreads();
  {
    const int w = tid >> 6, dk = tid & 63;
    const float* wq = W_QT + (size_t)(w * 96) * 64 + dk;
    const float* xw = xp + w * 96;
    float a0 = 0.f, a1 = 0.f, a2 = 0.f;
#pragma unroll
    for (int i = 0; i < 96; i += 3) {
      a0 += xw[i + 0] * wq[(size_t)(i + 0) * 64];
      a1 += xw[i + 1] * wq[(size_t)(i + 1) * 64];
      a2 += xw[i + 2] * wq[(size_t)(i + 2) * 64];
    }
    qtp[w][dk] = (a0 + a1) + a2;
  }
  __syncthreads();
  if (tid < 64) {
    int lane = tid;
    float qtv = qtp[0][lane] + qtp[1][lane] + qtp[2][lane] + qtp[3][lane];
    float qsv = qs_s[lane];
    float lt[4], ls[4];
#pragma unroll
    for (int h = 0; h < 4; ++h) {
      float p = qtv * K_T[h * 64 + lane];
#pragma unroll
      for (int off = 32; off > 0; off >>= 1) p += __shfl_xor(p, off);
      lt[h] = p;
      float p2 = qsv * K_S[h * 64 + lane];
#pragma unroll
      for (int off = 32; off > 0; off >>= 1) p2 += __shfl_xor(p2, off);
      ls[h] = p2;
    }
    if (lane == 0) {
      const float scale = 0.125f;
      float mt = fmaxf(fmaxf(lt[0], lt[1]), fmaxf(lt[2], lt[3]));
      float ms = fmaxf(fmaxf(ls[0], ls[1]), fmaxf(ls[2], ls[3]));
      float et[4], es[4], st = 0.f, ss = 0.f;
#pragma unroll
      for (int h = 0; h < 4; ++h) {
        et[h] = __expf((lt[h] - mt) * scale); st += et[h];
        es[h] = __expf((ls[h] - ms) * scale); ss += es[h];
      }
#pragma unroll
      for (int h = 0; h < 4; ++h) {
        at_g[b * 8 + h] = et[h] / st;
        at_g[b * 8 + 4 + h] = es[h] / ss;
      }
    }
  }
}

// ets_bf[b][n][16] (k>=10 zero) from attention-mixed V  (128 blocks)
__global__ __launch_bounds__(256) void k_ets(const float* __restrict__ at_g,
                                             const float* __restrict__ V_T,
                                             const float* __restrict__ V_S,
                                             unsigned short* __restrict__ ets_bf) {
  int idx = blockIdx.x * 256 + threadIdx.x;
  int b = idx >> 11, n = idx & 2047;
  const float* at = at_g + b * 8;
  float a0 = at[0], a1 = at[1], a2 = at[2], a3 = at[3];
  float s0 = at[4], s1 = at[5], s2 = at[6], s3 = at[7];
  float v[10];
#pragma unroll
  for (int c = 0; c < 10; ++c) {
    int o = n * 10 + c;
    v[c] = a0 * V_T[o] + a1 * V_T[20480 + o] + a2 * V_T[40960 + o] + a3 * V_T[61440 + o] +
           s0 * V_S[o] + s1 * V_S[20480 + o] + s2 * V_S[40960 + o] + s3 * V_S[61440 + o];
  }
  uint4 lo, hi;
  lo.x = (unsigned)f2bf(v[0]) | ((unsigned)f2bf(v[1]) << 16);
  lo.y = (unsigned)f2bf(v[2]) | ((unsigned)f2bf(v[3]) << 16);
  lo.z = (unsigned)f2bf(v[4]) | ((unsigned)f2bf(v[5]) << 16);
  lo.w = (unsigned)f2bf(v[6]) | ((unsigned)f2bf(v[7]) << 16);
  hi.x = (unsigned)f2bf(v[8]) | ((unsigned)f2bf(v[9]) << 16);
  hi.y = 0; hi.z = 0; hi.w = 0;
  *(uint4*)(ets_bf + (size_t)idx * 16) = lo;
  *(uint4*)(ets_bf + (size_t)idx * 16 + 8) = hi;
}

// ------- phase C producer: MFMA x @ {W2,Ws0,Ws1} + fused x n-sum partials -------

__global__ __launch_bounds__(256) void k_zb(const float* __restrict__ x,
                                            const float* __restrict__ W2,
                                            const float* __restrict__ Ws0,
                                            const float* __restrict__ Ws1,
                                            unsigned char* __restrict__ z0Tf,
                                            unsigned short* __restrict__ bias0T,
                                            unsigned short* __restrict__ bias1T,
                                            float* __restrict__ pxmn_p) {
  __shared__ __align__(16) unsigned short wlds[3072];
  __shared__ __align__(16) unsigned char zsh[32 * 272];
  __shared__ __align__(16) unsigned char b0sh[32 * 528];
  __shared__ __align__(16) unsigned char b1sh[32 * 528];
  __shared__ float psum[4][32];
  const int tid = threadIdx.x;
  for (int j = tid; j < 3072; j += 256) {
    int mat = j >> 10, rr = j & 1023, k = rr >> 5, d = rr & 31;
    const float* Wsrc = (mat == 0) ? W2 : (mat == 1 ? Ws0 : Ws1);
    wlds[(mat * 32 + d) * 32 + k] = f2bf(Wsrc[rr]);
  }
  __syncthreads();

  const int lane = tid & 63, w = tid >> 6;
  const int cl = lane & 15, g = lane >> 4;
  const int bx = blockIdx.x;
  const int b = bx / 96, r = bx % 96, t = r >> 3, mc = r & 7;

  bf16x8 bfr[6];
#pragma unroll
  for (int dt = 0; dt < 6; ++dt)
    bfr[dt] = *(const bf16x8*)(wlds + (dt * 16 + cl) * 32 + g * 8);

  const float* gx = x + ((size_t)(b * 2048 + mc * 256 + w * 64 + cl) * 12 + t) * 32 + g * 8;

  float4 sx0 = {0.f, 0.f, 0.f, 0.f}, sx1 = {0.f, 0.f, 0.f, 0.f};
#pragma unroll
  for (int i = 0; i < 4; ++i) {
    const float* xp = gx + (size_t)i * 16 * 384;
    float4 v0 = *(const float4*)xp;
    float4 v1 = *(const float4*)(xp + 4);
    sx0.x += v0.x; sx0.y += v0.y; sx0.z += v0.z; sx0.w += v0.w;
    sx1.x += v1.x; sx1.y += v1.y; sx1.z += v1.z; sx1.w += v1.w;
    bf16x8 af;
    af[0] = (__bf16)v0.x; af[1] = (__bf16)v0.y; af[2] = (__bf16)v0.z; af[3] = (__bf16)v0.w;
    af[4] = (__bf16)v1.x; af[5] = (__bf16)v1.y; af[6] = (__bf16)v1.z; af[7] = (__bf16)v1.w;
    f32x4 acc[6];
#pragma unroll
    for (int dt = 0; dt < 6; ++dt)
      acc[dt] = __builtin_amdgcn_mfma_f32_16x16x32_bf16(af, bfr[dt],
                                                        (f32x4){0.f, 0.f, 0.f, 0.f}, 0, 0, 0);
    const int ml = w * 64 + i * 16 + g * 4;
    const int pb = ((ml >> 7) << 7) + perm7(ml & 127);
#pragma unroll
    for (int dt = 0; dt < 2; ++dt) {
      unsigned u = __builtin_amdgcn_cvt_pk_fp8_f32(acc[dt][0], acc[dt][1], 0, false);
      u = __builtin_amdgcn_cvt_pk_fp8_f32(acc[dt][2], acc[dt][3], (int)u, true);
      *(unsigned*)(zsh + (dt * 16 + cl) * 272 + pb) = u;
    }
#pragma unroll
    for (int dt = 0; dt < 2; ++dt) {
      uint2 p;
      p.x = (unsigned)f2bf(acc[2 + dt][0]) | ((unsigned)f2bf(acc[2 + dt][1]) << 16);
      p.y = (unsigned)f2bf(acc[2 + dt][2]) | ((unsigned)f2bf(acc[2 + dt][3]) << 16);
      *(uint2*)(b0sh + (dt * 16 + cl) * 528 + ml * 2) = p;
      uint2 q;
      q.x = (unsigned)f2bf(acc[4 + dt][0]) | ((unsigned)f2bf(acc[4 + dt][1]) << 16);
      q.y = (unsigned)f2bf(acc[4 + dt][2]) | ((unsigned)f2bf(acc[4 + dt][3]) << 16);
      *(uint2*)(b1sh + (dt * 16 + cl) * 528 + ml * 2) = q;
    }
  }
#pragma unroll
  for (int off = 1; off < 16; off <<= 1) {
    sx0.x += __shfl_xor(sx0.x, off); sx0.y += __shfl_xor(sx0.y, off);
    sx0.z += __shfl_xor(sx0.z, off); sx0.w += __shfl_xor(sx0.w, off);
    sx1.x += __shfl_xor(sx1.x, off); sx1.y += __shfl_xor(sx1.y, off);
    sx1.z += __shfl_xor(sx1.z, off); sx1.w += __shfl_xor(sx1.w, off);
  }
  if (cl == 0) {
    *(float4*)(&psum[w][g * 8]) = sx0;
    *(float4*)(&psum[w][g * 8 + 4]) = sx1;
  }
  __syncthreads();
  if (tid < 32)
    pxmn_p[(size_t)((b * 12 + t) * 8 + mc) * 32 + tid] =
        psum[0][tid] + psum[1][tid] + psum[2][tid] + psum[3][tid];

  const int d = tid >> 3, c8 = tid & 7;
  {
    uint4 v0 = *(const uint4*)(zsh + d * 272 + c8 * 32);
    uint4 v1 = *(const uint4*)(zsh + d * 272 + c8 * 32 + 16);
    unsigned char* zdst =
        z0Tf + (size_t)b * 786432 + (size_t)(t * 32 + d) * 2048 + mc * 256 + c8 * 32;
    *(uint4*)zdst = v0;
    *(uint4*)(zdst + 16) = v1;
  }
  {
    char* bdst0 = (char*)(bias0T + (size_t)b * 786432 + (size_t)(t * 32 + d) * 2048 +
                          mc * 256 + c8 * 32);
    char* bdst1 = (char*)(bias1T + (size_t)b * 786432 + (size_t)(t * 32 + d) * 2048 +
                          mc * 256 + c8 * 32);
#pragma unroll
    for (int q = 0; q < 4; ++q) {
      *(uint4*)(bdst0 + q * 16) = *(const uint4*)(b0sh + d * 528 + c8 * 64 + q * 16);
      *(uint4*)(bdst1 + q * 16) = *(const uint4*)(b1sh + d * 528 + c8 * 64 + q * 16);
    }
  }
}

// -------- fused: scores (ets,dis -> exp, fp8, LDS) + PV GEMM + 1/rowsum epilogue -----
// Per K-step (128 nodes): score MFMA (swapped operands, K=16) -> exp -> pack into the
// PV A-buffer (perm7 + XOR swizzle, matching aoff reads); PV fp8 MFMA vs staged Z.

template <int OUT_F32>
__global__ __launch_bounds__(256, 2) void gemm_fused(const unsigned short* __restrict__ ets_bf,
                                                     const float* __restrict__ dis,
                                                     const unsigned char* __restrict__ Bt,
                                                     const unsigned short* __restrict__ biasT,
                                                     void* __restrict__ outp) {
  const int tid = threadIdx.x;
  const int lane = tid & 63;
  const int w = tid >> 6;        // wave 0..3
  const int cl = lane & 15;
  const int g = lane >> 4;
  const int wr = w >> 1, wc = w & 1;
  const int orig = blockIdx.x;
  const int wg = (orig & 7) * 64 + (orig >> 3);
  const int b = wg >> 5;
  const int w32 = wg & 31;
  const int m0 = ((w32 >> 1) & 15) << 7;
  const int c0 = (w32 & 1) * 192;

  // LDS: P[16KB] | Z dbuf 2x24KB
  __shared__ __align__(16) unsigned char smem[16384 + 49152];
  __shared__ float rs_lds[128];

  const unsigned char* gets = (const unsigned char*)(ets_bf + (size_t)b * 32768);
  const unsigned char* bBase = Bt + (size_t)b * 786432;
  const int jx = ((tid & 7) ^ ((tid >> 3) & 7)) << 4;
  const unsigned char* gB = bBase + (size_t)(c0 + (tid >> 3)) * 2048 + jx;

  // score B-operand: strips of 16 m-rows; wave w owns strips 2w, 2w+1 (rows 32w..32w+31)
  bf16x8 strip[2];
#pragma unroll
  for (int s = 0; s < 2; ++s) {
    uint4 a = *(const uint4*)(ets_bf + ((size_t)b * 2048 + m0 + (2 * w + s) * 16 + cl) * 16 +
                              (g & 1) * 8);
    if (g >= 2) { a.x = 0; a.y = 0; a.z = 0; a.w = 0; }
    strip[s] = __builtin_bit_cast(bf16x8, a);
  }

  // PV offsets: A (P) at smem base 0; B (Z) relative within its buffer
  int aoff[2][4], boff[2][6];
#pragma unroll
  for (int kkp = 0; kkp < 2; ++kkp) {
    int c = ((lane >> 4) << 1) + kkp;
#pragma unroll
    for (int f = 0; f < 4; ++f) {
      int rA = wr * 64 + f * 16 + (lane & 15);
      aoff[kkp][f] = rA * 128 + ((c ^ (rA & 7)) << 4);
    }
#pragma unroll
    for (int n = 0; n < 6; ++n) {
      int rB = wc * 96 + n * 16 + (lane & 15);
      boff[kkp][n] = rB * 128 + ((c ^ (rB & 7)) << 4);
    }
  }

  f32x4 acc[4][6] = {};
  float rowsum[2] = {0.f, 0.f};

#define STAGEZ(BUF, KT)                                                            \
  {                                                                                \
    _Pragma("unroll") for (int ii = 0; ii < 6; ++ii)                               \
        gload16(gB + (size_t)ii * 65536 + (KT)*128,                                \
                smem + 16384 + (BUF) + ii * 4096 + tid * 16);                      \
  }

  STAGEZ(0, 0);

  int cur = 0;
  for (int kt = 0; kt < 16; ++kt) {
    const int nxt = cur ^ 24576;
    if (kt < 15) STAGEZ(nxt, kt + 1);

    // ---- score phase: nodes kt*128 .. +127 ----
    uint4 nraw[8];
#pragma unroll
    for (int n = 0; n < 8; ++n) {
      uint4 r = *(const uint4*)(gets + (size_t)(kt * 128 + n * 16 + cl) * 32 + (g & 1) * 16);
      if (g >= 2) { r.x = 0; r.y = 0; r.z = 0; r.w = 0; }
      nraw[n] = r;
    }
#pragma unroll
    for (int s = 0; s < 2; ++s) {
      const int rA = (2 * w + s) * 16 + cl;
      const float* drow = dis + (size_t)(m0 + rA) * 2048 + kt * 128 + (g << 2);
      f32x4 sc[8];
#pragma unroll
      for (int n = 0; n < 8; ++n)
        sc[n] = __builtin_amdgcn_mfma_f32_16x16x32_bf16(__builtin_bit_cast(bf16x8, nraw[n]),
                                                        strip[s], (f32x4){0.f, 0.f, 0.f, 0.f},
                                                        0, 0, 0);
      const int sw = (rA & 7) << 4;
#pragma unroll
      for (int n = 0; n < 8; ++n) {
        float4 dv = *(const float4*)(drow + n * 16);
        float e0 = __expf(fmaxf(sc[n][0] + dv.x, 0.f));
        float e1 = __expf(fmaxf(sc[n][1] + dv.y, 0.f));
        float e2 = __expf(fmaxf(sc[n][2] + dv.z, 0.f));
        float e3 = __expf(fmaxf(sc[n][3] + dv.w, 0.f));
        rowsum[s] += (e0 + e1) + (e2 + e3);
        int ml = n * 16 + (g << 2);
        int pb = perm7(ml);
        int byte = rA * 128 + (((pb & 0xF0) ^ sw) | (pb & 15));
        unsigned u = __builtin_amdgcn_cvt_pk_fp8_f32(e0, e1, 0, false);
        u = __builtin_amdgcn_cvt_pk_fp8_f32(e2, e3, (int)u, true);
        *(unsigned*)(smem + byte) = u;
      }
    }
    asm volatile("s_waitcnt lgkmcnt(0)" ::: "memory");
    if (kt < 15) {
      asm volatile("s_waitcnt vmcnt(6)" ::: "memory");  // Z kt landed; kt+1 in flight
    } else {
      asm volatile("s_waitcnt vmcnt(0)" ::: "memory");
    }
    __builtin_amdgcn_s_barrier();

    // ---- PV phase ----
#pragma unroll
    for (int kkp = 0; kkp < 2; ++kkp) {
      ulong2 av[4], bv[6];
#pragma unroll
      for (int f = 0; f < 4; ++f) av[f] = *(const ulong2*)(smem + aoff[kkp][f]);
#pragma unroll
      for (int n = 0; n < 6; ++n)
        bv[n] = *(const ulong2*)(smem + 16384 + cur + boff[kkp][n]);
#pragma unroll
      for (int m = 0; m < 4; ++m)
#pragma unroll
        for (int n = 0; n < 6; ++n)
          acc[m][n] = __builtin_amdgcn_mfma_f32_16x16x32_fp8_fp8(
              (long)av[m].x, (long)bv[n].x, acc[m][n], 0, 0, 0);
#pragma unroll
      for (int m = 0; m < 4; ++m)
#pragma unroll
        for (int n = 0; n < 6; ++n)
          acc[m][n] = __builtin_amdgcn_mfma_f32_16x16x32_fp8_fp8(
              (long)av[m].y, (long)bv[n].y, acc[m][n], 0, 0, 0);
    }
    __builtin_amdgcn_s_barrier();
    asm volatile("" ::: "memory");  // compiler fence: no hoist of next pack above barrier
    cur = nxt;
  }
#undef STAGEZ

  // ---- rowsum exchange ----
  rowsum[0] += __shfl_xor(rowsum[0], 16);
  rowsum[0] += __shfl_xor(rowsum[0], 32);
  rowsum[1] += __shfl_xor(rowsum[1], 16);
  rowsum[1] += __shfl_xor(rowsum[1], 32);
  if (lane < 16) {
    rs_lds[(2 * w + 0) * 16 + cl] = rowsum[0];
    rs_lds[(2 * w + 1) * 16 + cl] = rowsum[1];
  }
  __syncthreads();

  const int epcl = lane & 15;
  const int r4 = (lane >> 4) << 2;
  const unsigned short* bi = biasT + (size_t)b * 786432;
  if (OUT_F32) {
    float* o = (float*)outp + (size_t)b * 786432;
#pragma unroll
    for (int m = 0; m < 4; ++m) {
      int rloc = wr * 64 + m * 16 + r4;
      int row0 = m0 + rloc;
      float4 rsv = *(const float4*)(rs_lds + rloc);
      float i0 = 1.0f / rsv.x, i1 = 1.0f / rsv.y, i2 = 1.0f / rsv.z, i3 = 1.0f / rsv.w;
#pragma unroll
      for (int n = 0; n < 6; ++n) {
        int col = c0 + wc * 96 + n * 16 + epcl;
        uint2 bw = *(const uint2*)(bi + ((size_t)col << 11) + row0);
        o[(size_t)(row0 + 0) * 384 + col] =
            acc[m][n][0] * i0 + bf2f((unsigned short)(bw.x & 0xffff));
        o[(size_t)(row0 + 1) * 384 + col] =
            acc[m][n][1] * i1 + bf2f((unsigned short)(bw.x >> 16));
        o[(size_t)(row0 + 2) * 384 + col] =
            acc[m][n][2] * i2 + bf2f((unsigned short)(bw.y & 0xffff));
        o[(size_t)(row0 + 3) * 384 + col] =
            acc[m][n][3] * i3 + bf2f((unsigned short)(bw.y >> 16));
      }
    }
  } else {
    unsigned char* o = (unsigned char*)outp + (size_t)b * 786432;
#pragma unroll
    for (int m = 0; m < 4; ++m) {
      int rloc = wr * 64 + m * 16 + r4;
      int row0 = m0 + rloc;
      float4 rsv = *(const float4*)(rs_lds + rloc);
      float i0 = 1.0f / rsv.x, i1 = 1.0f / rsv.y, i2 = 1.0f / rsv.z, i3 = 1.0f / rsv.w;
      const int pb = ((row0 >> 7) << 7) + perm7(row0 & 127);
#pragma unroll
      for (int n = 0; n < 6; ++n) {
        int col = c0 + wc * 96 + n * 16 + epcl;
        uint2 bw = *(const uint2*)(bi + ((size_t)col << 11) + row0);
        float v0 = acc[m][n][0] * i0 + bf2f((unsigned short)(bw.x & 0xffff));
        float v1 = acc[m][n][1] * i1 + bf2f((unsigned short)(bw.x >> 16));
        float v2 = acc[m][n][2] * i2 + bf2f((unsigned short)(bw.y & 0xffff));
        float v3 = acc[m][n][3] * i3 + bf2f((unsigned short)(bw.y >> 16));
        unsigned u = __builtin_amdgcn_cvt_pk_fp8_f32(v0, v1, 0, false);
        u = __builtin_amdgcn_cvt_pk_fp8_f32(v2, v3, (int)u, true);
        *(unsigned*)(o + (size_t)col * 2048 + pb) = u;
      }
    }
  }
}

// ---------------- launch ----------------

extern "C" void kernel_launch(void* const* d_in, const int* in_sizes, int n_in,
                              void* d_out, int out_size, void* d_ws, size_t ws_size,
                              hipStream_t stream) {
  const float* x = (const float*)d_in[0];
  const float* dis = (const float*)d_in[1];
  const float* K_S = (const float*)d_in[2];
  const float* V_S = (const float*)d_in[3];
  const float* K_T = (const float*)d_in[4];
  const float* V_T = (const float*)d_in[5];
  const float* W_Q0 = (const float*)d_in[6];
  const float* W_QS = (const float*)d_in[7];
  const float* W_QT = (const float*)d_in[8];
  const float* W2 = (const float*)d_in[9];
  const float* W_s0 = (const float*)d_in[10];
  const float* W_s1 = (const float*)d_in[11];

  char* ws = (char*)d_ws;
  float* pxmn_p = (float*)(ws + 0);                          //    196,608 B
  float* pqs = (float*)(ws + 196608);                        //  4,194,304 B
  unsigned short* ets_bf = (unsigned short*)(ws + 4390912);  //  1,048,576 B
  unsigned char* z0Tf = (unsigned char*)(ws + 5439488);      // 12,582,912 B
  unsigned char* z1Tf = (unsigned char*)(ws + 18022400);     // 12,582,912 B
  unsigned short* bias0T = (unsigned short*)(ws + 30605312); // 25,165,824 B
  unsigned short* bias1T = (unsigned short*)(ws + 55771136); // 25,165,824 B
  float* at_g = (float*)(ws + 80936960);                     //        512 B

  k_qs<<<1024, 256, 0, stream>>>(x, W_Q0, W_QS, pqs);
  k_zb<<<1536, 256, 0, stream>>>(x, W2, W_s0, W_s1, z0Tf, bias0T, bias1T, pxmn_p);
  k_head<<<16, 256, 0, stream>>>(pqs, pxmn_p, W_Q0, W_QT, K_T, K_S, at_g);
  k_ets<<<128, 256, 0, stream>>>(at_g, V_T, V_S, ets_bf);
  gemm_fused<0><<<512, 256, 0, stream>>>(ets_bf, dis, z0Tf, bias0T, (void*)z1Tf);
  gemm_fused<1><<<512, 256, 0, stream>>>(ets_bf, dis, z1Tf, bias1T, d_out);
}

// Round 18
// 194.826 us; speedup vs baseline: 1.4017x; 1.4017x over previous
//
#include <hip/hip_runtime.h>

typedef __bf16 bf16x8 __attribute__((ext_vector_type(8)));
typedef float f32x4 __attribute__((ext_vector_type(4)));

__device__ __forceinline__ unsigned short f2bf(float f) {
  unsigned u = __builtin_bit_cast(unsigned, f);
  u += 0x7fffu + ((u >> 16) & 1u);
  return (unsigned short)(u >> 16);
}
__device__ __forceinline__ float bf2f(unsigned short h) {
  unsigned u = ((unsigned)h) << 16;
  return __builtin_bit_cast(float, u);
}
__device__ __forceinline__ void gload16(const void* g, void* l) {
  __builtin_amdgcn_global_load_lds((const __attribute__((address_space(1))) void*)g,
                                   (__attribute__((address_space(3))) void*)l, 16, 0, 0);
}
// byte permutation within a 128-byte K-panel row: k = kk*32+g*8+e -> byte g*32+kk*8+e
__device__ __forceinline__ int perm7(int x) {
  return ((x >> 3) & 3) * 32 + ((x >> 5) << 3) + (x & 7);
}

// ---------------- phase A ----------------

// Per block (2 n-values): mean_t(x) -> @W_Q0 -> contract with 64 W_QS rows -> pqs[blk]
__global__ __launch_bounds__(256) void k_qs(const float* __restrict__ x,
                                            const float* __restrict__ W_Q0,
                                            const float* __restrict__ W_QS,
                                            float* __restrict__ pqs) {
  __shared__ __align__(16) float w0[1024];
  __shared__ __align__(16) float lm[1024];
  __shared__ float lq[1024];
  __shared__ float red[4][16][64];
  const int tid = threadIdx.x;
#pragma unroll
  for (int i = 0; i < 4; ++i) w0[tid + i * 256] = W_Q0[tid + i * 256];
  const int n0 = blockIdx.x * 2;

  {
    const int b = tid >> 4, r = tid & 15, n = r >> 3, k4 = r & 7;
    const float4* xp = (const float4*)(x + ((size_t)(b * 2048 + n0 + n) * 12) * 32) + k4;
    float4 s0 = xp[0], s1 = xp[8], s2 = xp[16];
    float4 s3 = xp[24], s4 = xp[32], s5 = xp[40];
#pragma unroll
    for (int t = 6; t < 12; ++t) {
      float4 v = xp[t * 8];
      s0.x += v.x; s0.y += v.y; s0.z += v.z; s0.w += v.w;
      float4 tmp = s0; s0 = s1; s1 = s2; s2 = s3; s3 = s4; s4 = s5; s5 = tmp;
    }
    float4 m;
    m.x = (s0.x + s1.x + s2.x) + (s3.x + s4.x + s5.x);
    m.y = (s0.y + s1.y + s2.y) + (s3.y + s4.y + s5.y);
    m.z = (s0.z + s1.z + s2.z) + (s3.z + s4.z + s5.z);
    m.w = (s0.w + s1.w + s2.w) + (s3.w + s4.w + s5.w);
    const float inv12 = 1.0f / 12.0f;
    m.x *= inv12; m.y *= inv12; m.z *= inv12; m.w *= inv12;
    *(float4*)(lm + (b * 2 + n) * 32 + k4 * 4) = m;
  }
  __syncthreads();
#pragma unroll
  for (int j = 0; j < 4; ++j) {
    int i = tid + j * 256;
    int bn = i >> 5, q = i & 31;
    const float* mrow = &lm[bn * 32];
    float a = 0.f;
#pragma unroll
    for (int k = 0; k < 32; ++k) a += mrow[k] * w0[k * 32 + q];
    lq[i] = a;
  }
  __syncthreads();
  const int lane = tid & 63, w = tid >> 6;
  float acc[16];
#pragma unroll
  for (int b = 0; b < 16; ++b) acc[b] = 0.f;
#pragma unroll
  for (int rl = 0; rl < 16; ++rl) {
    int r = w * 16 + rl;
    float wv = W_QS[(size_t)(n0 * 32 + r) * 64 + lane];
#pragma unroll
    for (int b = 0; b < 16; ++b) acc[b] += lq[b * 64 + r] * wv;
  }
#pragma unroll
  for (int b = 0; b < 16; ++b) red[w][b][lane] = acc[b];
  __syncthreads();
#pragma unroll
  for (int it = 0; it < 4; ++it) {
    int idx = tid + it * 256;
    float s = red[0][idx >> 6][idx & 63] + red[1][idx >> 6][idx & 63] +
              red[2][idx >> 6][idx & 63] + red[3][idx >> 6][idx & 63];
    pqs[(size_t)blockIdx.x * 1024 + idx] = s;
  }
}

// Head-attention weights: pqs/pxmn_p reduce + qt + softmax -> at_g[16][8]
__global__ __launch_bounds__(256) void k_head(const float* __restrict__ pqs,
                                              const float* __restrict__ pxmn_p,
                                              const float* __restrict__ W_Q0,
                                              const float* __restrict__ W_QT,
                                              const float* __restrict__ K_T,
                                              const float* __restrict__ K_S,
                                              float* __restrict__ at_g) {
  const int b = blockIdx.x, tid = threadIdx.x;
  __shared__ float red[4][64];
  __shared__ float qs_s[64];
  __shared__ float xmn_s[384];
  __shared__ float xp[384];
  __shared__ float qtp[4][64];

  {
    const int q = tid >> 6, dk = tid & 63;
    const float* p = pqs + (size_t)(q * 256) * 1024 + b * 64 + dk;
    float s0 = 0.f, s1 = 0.f, s2 = 0.f, s3 = 0.f;
#pragma unroll
    for (int c = 0; c < 256; c += 4) {
      s0 += p[(size_t)(c + 0) * 1024];
      s1 += p[(size_t)(c + 1) * 1024];
      s2 += p[(size_t)(c + 2) * 1024];
      s3 += p[(size_t)(c + 3) * 1024];
    }
    red[q][dk] = (s0 + s1) + (s2 + s3);
  }
  for (int i = tid; i < 384; i += 256) {
    int t = i >> 5, k = i & 31;
    const float* p = pxmn_p + (size_t)((b * 12 + t) * 8) * 32 + k;
    float v = ((p[0] + p[32]) + (p[64] + p[96])) + ((p[128] + p[160]) + (p[192] + p[224]));
    xmn_s[i] = v * (1.0f / 2048.0f);
  }
  __syncthreads();
  for (int i = tid; i < 384; i += 256) {
    int t = i >> 5, q = i & 31;
    float a = 0.f;
#pragma unroll
    for (int k = 0; k < 32; ++k) a += xmn_s[t * 32 + k] * W_Q0[k * 32 + q];
    xp[i] = a;
  }
  if (tid < 64) qs_s[tid] = red[0][tid] + red[1][tid] + red[2][tid] + red[3][tid];
  __syncthreads();
  {
    const int w = tid >> 6, dk = tid & 63;
    const float* wq = W_QT + (size_t)(w * 96) * 64 + dk;
    const float* xw = xp + w * 96;
    float a0 = 0.f, a1 = 0.f, a2 = 0.f;
#pragma unroll
    for (int i = 0; i < 96; i += 3) {
      a0 += xw[i + 0] * wq[(size_t)(i + 0) * 64];
      a1 += xw[i + 1] * wq[(size_t)(i + 1) * 64];
      a2 += xw[i + 2] * wq[(size_t)(i + 2) * 64];
    }
    qtp[w][dk] = (a0 + a1) + a2;
  }
  __syncthreads();
  if (tid < 64) {
    int lane = tid;
    float qtv = qtp[0][lane] + qtp[1][lane] + qtp[2][lane] + qtp[3][lane];
    float qsv = qs_s[lane];
    float lt[4], ls[4];
#pragma unroll
    for (int h = 0; h < 4; ++h) {
      float p = qtv * K_T[h * 64 + lane];
#pragma unroll
      for (int off = 32; off > 0; off >>= 1) p += __shfl_xor(p, off);
      lt[h] = p;
      float p2 = qsv * K_S[h * 64 + lane];
#pragma unroll
      for (int off = 32; off > 0; off >>= 1) p2 += __shfl_xor(p2, off);
      ls[h] = p2;
    }
    if (lane == 0) {
      const float scale = 0.125f;
      float mt = fmaxf(fmaxf(lt[0], lt[1]), fmaxf(lt[2], lt[3]));
      float ms = fmaxf(fmaxf(ls[0], ls[1]), fmaxf(ls[2], ls[3]));
      float et[4], es[4], st = 0.f, ss = 0.f;
#pragma unroll
      for (int h = 0; h < 4; ++h) {
        et[h] = __expf((lt[h] - mt) * scale); st += et[h];
        es[h] = __expf((ls[h] - ms) * scale); ss += es[h];
      }
#pragma unroll
      for (int h = 0; h < 4; ++h) {
        at_g[b * 8 + h] = et[h] / st;
        at_g[b * 8 + 4 + h] = es[h] / ss;
      }
    }
  }
}

// ets_bf[b][n][16] (k>=10 zero) from attention-mixed V  (128 blocks)
__global__ __launch_bounds__(256) void k_ets(const float* __restrict__ at_g,
                                             const float* __restrict__ V_T,
                                             const float* __restrict__ V_S,
                                             unsigned short* __restrict__ ets_bf) {
  int idx = blockIdx.x * 256 + threadIdx.x;
  int b = idx >> 11, n = idx & 2047;
  const float* at = at_g + b * 8;
  float a0 = at[0], a1 = at[1], a2 = at[2], a3 = at[3];
  float s0 = at[4], s1 = at[5], s2 = at[6], s3 = at[7];
  float v[10];
#pragma unroll
  for (int c = 0; c < 10; ++c) {
    int o = n * 10 + c;
    v[c] = a0 * V_T[o] + a1 * V_T[20480 + o] + a2 * V_T[40960 + o] + a3 * V_T[61440 + o] +
           s0 * V_S[o] + s1 * V_S[20480 + o] + s2 * V_S[40960 + o] + s3 * V_S[61440 + o];
  }
  uint4 lo, hi;
  lo.x = (unsigned)f2bf(v[0]) | ((unsigned)f2bf(v[1]) << 16);
  lo.y = (unsigned)f2bf(v[2]) | ((unsigned)f2bf(v[3]) << 16);
  lo.z = (unsigned)f2bf(v[4]) | ((unsigned)f2bf(v[5]) << 16);
  lo.w = (unsigned)f2bf(v[6]) | ((unsigned)f2bf(v[7]) << 16);
  hi.x = (unsigned)f2bf(v[8]) | ((unsigned)f2bf(v[9]) << 16);
  hi.y = 0; hi.z = 0; hi.w = 0;
  *(uint4*)(ets_bf + (size_t)idx * 16) = lo;
  *(uint4*)(ets_bf + (size_t)idx * 16 + 8) = hi;
}

// ------- phase B: MFMA adjacency (swapped operands) + softmax (no max) -> fp8 -------
// No LDS staging: ets (1MB, L2-resident) read directly per-lane as MFMA operands.
// LDS = transpose buffer only (~35KB) -> 4 blocks/CU. XCD-grouped work mapping.

__global__ __launch_bounds__(512, 4) void k_adj(const unsigned short* __restrict__ ets_bf,
                                                const float* __restrict__ dis,
                                                unsigned char* __restrict__ adjf) {
  __shared__ __align__(16) unsigned char Tws[8 * 4352];  // per-wave [16 rows][272B]
  __shared__ float st_sum[8][16];
  __shared__ float rowinv_s[16];

  const int tid = threadIdx.x;
  const int lane = tid & 63;
  const int w = tid >> 6;
  const int cl = lane & 15;
  const int g = lane >> 4;
  const int orig = blockIdx.x;
  const int work = (orig & 7) * 256 + (orig >> 3);  // XCD-resident work grouping
  const int b = work & 15;
  const int n0 = (work >> 4) << 4;

  const unsigned char* gets = (const unsigned char*)(ets_bf + (size_t)b * 32768);

  uint4 araw = *(const uint4*)(ets_bf + ((size_t)b * 2048 + n0 + cl) * 16 + (g & 1) * 8);
  if (g >= 2) { araw.x = 0; araw.y = 0; araw.z = 0; araw.w = 0; }
  bf16x8 strip = __builtin_bit_cast(bf16x8, araw);  // B operand: col=cl -> row n0+cl

  f32x4 acc[16];
  const int cbase = (w << 8) + cl;
#pragma unroll
  for (int n = 0; n < 16; ++n) {
    uint4 braw = *(const uint4*)(gets + (size_t)(cbase + n * 16) * 32 + (g & 1) * 16);
    if (g >= 2) { braw.x = 0; braw.y = 0; braw.z = 0; braw.w = 0; }
    bf16x8 nodes = __builtin_bit_cast(bf16x8, braw);  // A operand: row=cl -> node chunk
    acc[n] = __builtin_amdgcn_mfma_f32_16x16x32_bf16(nodes, strip,
                                                     (f32x4){0.f, 0.f, 0.f, 0.f}, 0, 0, 0);
  }

  // dis + relu + exp (no max shift: scores bounded ~1.5) + row sum
  const float* drow = dis + (size_t)(n0 + cl) * 2048 + (w << 8) + (g << 2);
  float lsum = 0.f;
#pragma unroll
  for (int n = 0; n < 16; ++n) {
    float4 dv = *(const float4*)(drow + n * 16);
    float e0 = __expf(fmaxf(acc[n][0] + dv.x, 0.f));
    float e1 = __expf(fmaxf(acc[n][1] + dv.y, 0.f));
    float e2 = __expf(fmaxf(acc[n][2] + dv.z, 0.f));
    float e3 = __expf(fmaxf(acc[n][3] + dv.w, 0.f));
    acc[n][0] = e0; acc[n][1] = e1; acc[n][2] = e2; acc[n][3] = e3;
    lsum += (e0 + e1) + (e2 + e3);
  }
  lsum += __shfl_xor(lsum, 16);
  lsum += __shfl_xor(lsum, 32);
  if (g == 0) st_sum[w][cl] = lsum;
  __syncthreads();
  if (tid < 16) {
    float s = st_sum[0][tid];
#pragma unroll
    for (int ww = 1; ww < 8; ++ww) s += st_sum[ww][tid];
    rowinv_s[tid] = 256.0f / s;  // x256 keeps fp8 in normal range
  }
  __syncthreads();

  const float inv = rowinv_s[cl];
  unsigned char* Tw = Tws + w * 4352;  // [16 rows][272B padded] per wave
#pragma unroll
  for (int n = 0; n < 16; ++n) {
    int ml = n * 16 + (g << 2);
    int pb = ((ml >> 7) << 7) + perm7(ml & 127);
    unsigned u = __builtin_amdgcn_cvt_pk_fp8_f32(acc[n][0] * inv, acc[n][1] * inv, 0, false);
    u = __builtin_amdgcn_cvt_pk_fp8_f32(acc[n][2] * inv, acc[n][3] * inv, (int)u, true);
    *(unsigned*)(Tw + cl * 272 + pb) = u;
  }
  asm volatile("s_waitcnt lgkmcnt(0)" ::: "memory");  // wave-private region; drain writes

  // writeback: 4 rows x 256B contiguous per instruction
  unsigned char* obase = adjf + ((size_t)(b * 2048 + n0)) * 2048 + (w << 8);
  const int rw = lane >> 4;             // row within 4-row group
  const int cc = (lane & 15) * 16;      // 16 lanes cover 256B of one row
#pragma unroll
  for (int q = 0; q < 4; ++q) {
    int row = q * 4 + rw;
    uint4 v = *(const uint4*)(Tw + row * 272 + cc);
    *(uint4*)(obase + (size_t)row * 2048 + cc) = v;
  }
}

// ------- phase C producer: MFMA x @ {W2,Ws0,Ws1} + fused x n-sum partials -------

__global__ __launch_bounds__(256) void k_zb(const float* __restrict__ x,
                                            const float* __restrict__ W2,
                                            const float* __restrict__ Ws0,
                                            const float* __restrict__ Ws1,
                                            unsigned char* __restrict__ z0Tf,
                                            unsigned short* __restrict__ bias0T,
                                            unsigned short* __restrict__ bias1T,
                                            float* __restrict__ pxmn_p) {
  __shared__ __align__(16) unsigned short wlds[3072];
  __shared__ __align__(16) unsigned char zsh[32 * 272];
  __shared__ __align__(16) unsigned char b0sh[32 * 528];
  __shared__ __align__(16) unsigned char b1sh[32 * 528];
  __shared__ float psum[4][32];
  const int tid = threadIdx.x;
  for (int j = tid; j < 3072; j += 256) {
    int mat = j >> 10, rr = j & 1023, k = rr >> 5, d = rr & 31;
    const float* Wsrc = (mat == 0) ? W2 : (mat == 1 ? Ws0 : Ws1);
    wlds[(mat * 32 + d) * 32 + k] = f2bf(Wsrc[rr]);
  }
  __syncthreads();

  const int lane = tid & 63, w = tid >> 6;
  const int cl = lane & 15, g = lane >> 4;
  const int bx = blockIdx.x;
  const int b = bx / 96, r = bx % 96, t = r >> 3, mc = r & 7;

  bf16x8 bfr[6];
#pragma unroll
  for (int dt = 0; dt < 6; ++dt)
    bfr[dt] = *(const bf16x8*)(wlds + (dt * 16 + cl) * 32 + g * 8);

  const float* gx = x + ((size_t)(b * 2048 + mc * 256 + w * 64 + cl) * 12 + t) * 32 + g * 8;

  float4 sx0 = {0.f, 0.f, 0.f, 0.f}, sx1 = {0.f, 0.f, 0.f, 0.f};
#pragma unroll
  for (int i = 0; i < 4; ++i) {
    const float* xp = gx + (size_t)i * 16 * 384;
    float4 v0 = *(const float4*)xp;
    float4 v1 = *(const float4*)(xp + 4);
    sx0.x += v0.x; sx0.y += v0.y; sx0.z += v0.z; sx0.w += v0.w;
    sx1.x += v1.x; sx1.y += v1.y; sx1.z += v1.z; sx1.w += v1.w;
    bf16x8 af;
    af[0] = (__bf16)v0.x; af[1] = (__bf16)v0.y; af[2] = (__bf16)v0.z; af[3] = (__bf16)v0.w;
    af[4] = (__bf16)v1.x; af[5] = (__bf16)v1.y; af[6] = (__bf16)v1.z; af[7] = (__bf16)v1.w;
    f32x4 acc[6];
#pragma unroll
    for (int dt = 0; dt < 6; ++dt)
      acc[dt] = __builtin_amdgcn_mfma_f32_16x16x32_bf16(af, bfr[dt],
                                                        (f32x4){0.f, 0.f, 0.f, 0.f}, 0, 0, 0);
    const int ml = w * 64 + i * 16 + g * 4;
    const int pb = ((ml >> 7) << 7) + perm7(ml & 127);
#pragma unroll
    for (int dt = 0; dt < 2; ++dt) {
      unsigned u = __builtin_amdgcn_cvt_pk_fp8_f32(acc[dt][0], acc[dt][1], 0, false);
      u = __builtin_amdgcn_cvt_pk_fp8_f32(acc[dt][2], acc[dt][3], (int)u, true);
      *(unsigned*)(zsh + (dt * 16 + cl) * 272 + pb) = u;
    }
#pragma unroll
    for (int dt = 0; dt < 2; ++dt) {
      uint2 p;
      p.x = (unsigned)f2bf(acc[2 + dt][0]) | ((unsigned)f2bf(acc[2 + dt][1]) << 16);
      p.y = (unsigned)f2bf(acc[2 + dt][2]) | ((unsigned)f2bf(acc[2 + dt][3]) << 16);
      *(uint2*)(b0sh + (dt * 16 + cl) * 528 + ml * 2) = p;
      uint2 q;
      q.x = (unsigned)f2bf(acc[4 + dt][0]) | ((unsigned)f2bf(acc[4 + dt][1]) << 16);
      q.y = (unsigned)f2bf(acc[4 + dt][2]) | ((unsigned)f2bf(acc[4 + dt][3]) << 16);
      *(uint2*)(b1sh + (dt * 16 + cl) * 528 + ml * 2) = q;
    }
  }
#pragma unroll
  for (int off = 1; off < 16; off <<= 1) {
    sx0.x += __shfl_xor(sx0.x, off); sx0.y += __shfl_xor(sx0.y, off);
    sx0.z += __shfl_xor(sx0.z, off); sx0.w += __shfl_xor(sx0.w, off);
    sx1.x += __shfl_xor(sx1.x, off); sx1.y += __shfl_xor(sx1.y, off);
    sx1.z += __shfl_xor(sx1.z, off); sx1.w += __shfl_xor(sx1.w, off);
  }
  if (cl == 0) {
    *(float4*)(&psum[w][g * 8]) = sx0;
    *(float4*)(&psum[w][g * 8 + 4]) = sx1;
  }
  __syncthreads();
  if (tid < 32)
    pxmn_p[(size_t)((b * 12 + t) * 8 + mc) * 32 + tid] =
        psum[0][tid] + psum[1][tid] + psum[2][tid] + psum[3][tid];

  const int d = tid >> 3, c8 = tid & 7;
  {
    uint4 v0 = *(const uint4*)(zsh + d * 272 + c8 * 32);
    uint4 v1 = *(const uint4*)(zsh + d * 272 + c8 * 32 + 16);
    unsigned char* zdst =
        z0Tf + (size_t)b * 786432 + (size_t)(t * 32 + d) * 2048 + mc * 256 + c8 * 32;
    *(uint4*)zdst = v0;
    *(uint4*)(zdst + 16) = v1;
  }
  {
    char* bdst0 = (char*)(bias0T + (size_t)b * 786432 + (size_t)(t * 32 + d) * 2048 +
                          mc * 256 + c8 * 32);
    char* bdst1 = (char*)(bias1T + (size_t)b * 786432 + (size_t)(t * 32 + d) * 2048 +
                          mc * 256 + c8 * 32);
#pragma unroll
    for (int q = 0; q < 4; ++q) {
      *(uint4*)(bdst0 + q * 16) = *(const uint4*)(b0sh + d * 528 + c8 * 64 + q * 16);
      *(uint4*)(bdst1 + q * 16) = *(const uint4*)(b1sh + d * 528 + c8 * 64 + q * 16);
    }
  }
}

// ---------------- phase C: (adj*256) @ z fp8 MFMA GEMM ----------------

template <int OUT_F32>
__global__ __launch_bounds__(256, 2) void gemm_adj(const unsigned char* __restrict__ adjf,
                                                   const unsigned char* __restrict__ Bt,
                                                   const unsigned short* __restrict__ biasT,
                                                   void* __restrict__ outp) {
  const int tid = threadIdx.x;
  const int lane = tid & 63;
  const int wid = tid >> 6;
  const int wr = wid >> 1, wc = wid & 1;
  const int orig = blockIdx.x;
  const int wg = (orig & 7) * 64 + (orig >> 3);
  const int b = wg >> 5;
  const int w32 = wg & 31;
  const int m0 = ((w32 >> 1) & 15) << 7;
  const int c0 = (w32 & 1) * 192;

  __shared__ __align__(16) unsigned char smem[81920];

  const unsigned char* aBase = adjf + ((size_t)b << 22);
  const unsigned char* bBase = Bt + (size_t)b * 786432;
  const int jx = ((tid & 7) ^ ((tid >> 3) & 7)) << 4;
  const unsigned char* gA = aBase + (size_t)(m0 + (tid >> 3)) * 2048 + jx;
  const unsigned char* gB = bBase + (size_t)(c0 + (tid >> 3)) * 2048 + jx;

  int aoff[2][4], boff[2][6];
#pragma unroll
  for (int kkp = 0; kkp < 2; ++kkp) {
    int c = ((lane >> 4) << 1) + kkp;
#pragma unroll
    for (int f = 0; f < 4; ++f) {
      int rA = wr * 64 + f * 16 + (lane & 15);
      aoff[kkp][f] = rA * 128 + ((c ^ (rA & 7)) << 4);
    }
#pragma unroll
    for (int n = 0; n < 6; ++n) {
      int rB = wc * 96 + n * 16 + (lane & 15);
      boff[kkp][n] = 16384 + rB * 128 + ((c ^ (rB & 7)) << 4);
    }
  }

  f32x4 acc[4][6] = {};

#define STAGE(BUF, KT)                                                               \
  {                                                                                  \
    _Pragma("unroll") for (int ii = 0; ii < 4; ++ii)                                 \
        gload16(gA + (size_t)ii * 65536 + (KT)*128, smem + (BUF) + ii * 4096 + tid * 16); \
    _Pragma("unroll") for (int ii = 0; ii < 6; ++ii)                                 \
        gload16(gB + (size_t)ii * 65536 + (KT)*128,                                  \
                smem + (BUF) + 16384 + ii * 4096 + tid * 16);                        \
  }

  STAGE(0, 0);

  int cur = 0;
  for (int kt = 0; kt < 16; ++kt) {
    const int nxt = cur ^ 40960;
    if (kt < 15) {
      STAGE(nxt, kt + 1);
      asm volatile("s_waitcnt vmcnt(10)" ::: "memory");
    } else {
      asm volatile("s_waitcnt vmcnt(0)" ::: "memory");
    }
    __builtin_amdgcn_s_barrier();
#pragma unroll
    for (int kkp = 0; kkp < 2; ++kkp) {
      ulong2 av[4], bv[6];
#pragma unroll
      for (int f = 0; f < 4; ++f) av[f] = *(const ulong2*)(smem + cur + aoff[kkp][f]);
#pragma unroll
      for (int n = 0; n < 6; ++n) bv[n] = *(const ulong2*)(smem + cur + boff[kkp][n]);
#pragma unroll
      for (int m = 0; m < 4; ++m)
#pragma unroll
        for (int n = 0; n < 6; ++n)
          acc[m][n] = __builtin_amdgcn_mfma_f32_16x16x32_fp8_fp8(
              (long)av[m].x, (long)bv[n].x, acc[m][n], 0, 0, 0);
#pragma unroll
      for (int m = 0; m < 4; ++m)
#pragma unroll
        for (int n = 0; n < 6; ++n)
          acc[m][n] = __builtin_amdgcn_mfma_f32_16x16x32_fp8_fp8(
              (long)av[m].y, (long)bv[n].y, acc[m][n], 0, 0, 0);
    }
    __builtin_amdgcn_s_barrier();
    cur = nxt;
  }
#undef STAGE

  const float inv256 = 0.00390625f;
  const int cl = lane & 15;
  const int r4 = (lane >> 4) << 2;
  const unsigned short* bi = biasT + (size_t)b * 786432;
  if (OUT_F32) {
    float* o = (float*)outp + (size_t)b * 786432;
#pragma unroll
    for (int m = 0; m < 4; ++m) {
      int row0 = m0 + wr * 64 + m * 16 + r4;
#pragma unroll
      for (int n = 0; n < 6; ++n) {
        int col = c0 + wc * 96 + n * 16 + cl;
        uint2 bw = *(const uint2*)(bi + ((size_t)col << 11) + row0);
        float bv0 = bf2f((unsigned short)(bw.x & 0xffff));
        float bv1 = bf2f((unsigned short)(bw.x >> 16));
        float bv2 = bf2f((unsigned short)(bw.y & 0xffff));
        float bv3 = bf2f((unsigned short)(bw.y >> 16));
        o[(size_t)(row0 + 0) * 384 + col] = acc[m][n][0] * inv256 + bv0;
        o[(size_t)(row0 + 1) * 384 + col] = acc[m][n][1] * inv256 + bv1;
        o[(size_t)(row0 + 2) * 384 + col] = acc[m][n][2] * inv256 + bv2;
        o[(size_t)(row0 + 3) * 384 + col] = acc[m][n][3] * inv256 + bv3;
      }
    }
  } else {
    unsigned char* o = (unsigned char*)outp + (size_t)b * 786432;
#pragma unroll
    for (int m = 0; m < 4; ++m) {
      int row0 = m0 + wr * 64 + m * 16 + r4;
      const int pb = ((row0 >> 7) << 7) + perm7(row0 & 127);
#pragma unroll
      for (int n = 0; n < 6; ++n) {
        int col = c0 + wc * 96 + n * 16 + cl;
        uint2 bw = *(const uint2*)(bi + ((size_t)col << 11) + row0);
        float v0 = acc[m][n][0] * inv256 + bf2f((unsigned short)(bw.x & 0xffff));
        float v1 = acc[m][n][1] * inv256 + bf2f((unsigned short)(bw.x >> 16));
        float v2 = acc[m][n][2] * inv256 + bf2f((unsigned short)(bw.y & 0xffff));
        float v3 = acc[m][n][3] * inv256 + bf2f((unsigned short)(bw.y >> 16));
        unsigned u = __builtin_amdgcn_cvt_pk_fp8_f32(v0, v1, 0, false);
        u = __builtin_amdgcn_cvt_pk_fp8_f32(v2, v3, (int)u, true);
        *(unsigned*)(o + (size_t)col * 2048 + pb) = u;
      }
    }
  }
}

// ---------------- launch ----------------

extern "C" void kernel_launch(void* const* d_in, const int* in_sizes, int n_in,
                              void* d_out, int out_size, void* d_ws, size_t ws_size,
                              hipStream_t stream) {
  const float* x = (const float*)d_in[0];
  const float* dis = (const float*)d_in[1];
  const float* K_S = (const float*)d_in[2];
  const float* V_S = (const float*)d_in[3];
  const float* K_T = (const float*)d_in[4];
  const float* V_T = (const float*)d_in[5];
  const float* W_Q0 = (const float*)d_in[6];
  const float* W_QS = (const float*)d_in[7];
  const float* W_QT = (const float*)d_in[8];
  const float* W2 = (const float*)d_in[9];
  const float* W_s0 = (const float*)d_in[10];
  const float* W_s1 = (const float*)d_in[11];

  char* ws = (char*)d_ws;
  float* pxmn_p = (float*)(ws + 0);                          //    196,608 B
  float* pqs = (float*)(ws + 196608);                        //  4,194,304 B
  unsigned short* ets_bf = (unsigned short*)(ws + 4390912);  //  1,048,576 B
  unsigned char* adjf = (unsigned char*)(ws + 5439488);      // 67,108,864 B
  unsigned char* z0Tf = (unsigned char*)(ws + 72548352);     // 12,582,912 B
  unsigned char* z1Tf = (unsigned char*)(ws + 85131264);     // 12,582,912 B
  unsigned short* bias0T = (unsigned short*)(ws + 97714176); // 25,165,824 B
  unsigned short* bias1T = (unsigned short*)(ws + 122880000);// 25,165,824 B
  float* at_g = (float*)(ws + 148045824);                    //        512 B

  k_qs<<<1024, 256, 0, stream>>>(x, W_Q0, W_QS, pqs);
  k_zb<<<1536, 256, 0, stream>>>(x, W2, W_s0, W_s1, z0Tf, bias0T, bias1T, pxmn_p);
  k_head<<<16, 256, 0, stream>>>(pqs, pxmn_p, W_Q0, W_QT, K_T, K_S, at_g);
  k_ets<<<128, 256, 0, stream>>>(at_g, V_T, V_S, ets_bf);
  k_adj<<<2048, 512, 0, stream>>>(ets_bf, dis, adjf);
  gemm_adj<0><<<512, 256, 0, stream>>>(adjf, z0Tf, bias0T, (void*)z1Tf);
  gemm_adj<1><<<512, 256, 0, stream>>>(adjf, z1Tf, bias1T, d_out);
}